// Round 1
// 419.091 us; speedup vs baseline: 1.0179x; 1.0179x over previous
//
#include <hip/hip_runtime.h>

// Row-wise softmax: out = exp(x) / sum(exp(x), axis=-1)
// x: (16384, 4096) fp32.
// One ROW PER WAVE (64 lanes x 16 float4 = 4096 cols), 4 waves/block,
// no __syncthreads, no LDS: pure shfl_xor butterfly reduction.
// exp(row) held in registers (64 VGPRs) -> exactly one global read +
// one global write per element, nontemporal (single-use streaming data).

typedef float fvec4 __attribute__((ext_vector_type(4)));

constexpr int COLS = 4096;
constexpr int THREADS = 256;
constexpr int WAVES_PER_BLOCK = THREADS / 64;       // 4 rows per block
constexpr int V4_PER_LANE = COLS / (64 * 4);        // 16 float4 per lane

__global__ __launch_bounds__(THREADS, 4) void softmax_rows_kernel(
    const float* __restrict__ x, float* __restrict__ out, int rows) {
  const int wave = threadIdx.x >> 6;
  const int lane = threadIdx.x & 63;
  const long long row = (long long)blockIdx.x * WAVES_PER_BLOCK + wave;
  if (row >= rows) return;  // rows % 4 == 0 here; never diverges

  const fvec4* __restrict__ xin =
      reinterpret_cast<const fvec4*>(x + row * COLS);
  fvec4* __restrict__ xout = reinterpret_cast<fvec4*>(out + row * COLS);

  // Read + exp, row resident in registers.
  fvec4 e[V4_PER_LANE];
  float local = 0.0f;
#pragma unroll
  for (int k = 0; k < V4_PER_LANE; ++k) {
    fvec4 v = __builtin_nontemporal_load(&xin[lane + k * 64]);
    e[k][0] = __expf(v[0]);
    e[k][1] = __expf(v[1]);
    e[k][2] = __expf(v[2]);
    e[k][3] = __expf(v[3]);
    local += (e[k][0] + e[k][1]) + (e[k][2] + e[k][3]);
  }

  // 64-lane butterfly: every lane ends with the full row sum.
#pragma unroll
  for (int off = 32; off > 0; off >>= 1)
    local += __shfl_xor(local, off, 64);

  const float inv = 1.0f / local;

#pragma unroll
  for (int k = 0; k < V4_PER_LANE; ++k) {
    fvec4 o = e[k] * inv;
    __builtin_nontemporal_store(o, &xout[lane + k * 64]);
  }
}

extern "C" void kernel_launch(void* const* d_in, const int* in_sizes, int n_in,
                              void* d_out, int out_size, void* d_ws,
                              size_t ws_size, hipStream_t stream) {
  const float* x = (const float*)d_in[0];
  float* out = (float*)d_out;
  const int rows = in_sizes[0] / COLS;  // 16384
  const int blocks = (rows + WAVES_PER_BLOCK - 1) / WAVES_PER_BLOCK;
  softmax_rows_kernel<<<blocks, THREADS, 0, stream>>>(x, out, rows);
}